// Round 4
// baseline (283.303 us; speedup 1.0000x reference)
//
#include <hip/hip_runtime.h>

// ---------------------------------------------------------------------------
// SingleHeadQKV: X@{Wq,Wk,Wv} -> rope+silu -> decay-masked QK^T -> @V -> GN
// B=2, T=4096, C=1024.
// R11: av = R10 (BM=128, 512thr, grid 256 = 1 blk/CU) + 3-buffer depth-2
// counted-vmcnt pipeline. R9 proved depth-2 null at 2 blk/CU (inter-block
// overlap masks it); at 1 blk/CU nothing masks latency -> T4's regime.
// score = BK 64->128: halves the number of exposed-latency stage windows
// (16->8 iters); LDS 64KB x 2 blk/CU = 128 <= 160KB, occupancy unchanged.
// qkv = R6 single-buffer (proven; do not touch).
// Staging = linear global_load_lds(16B) from PRE-SWIZZLED buffers (phys 16B
// chunk = (col>>3)^(row&7)); frag reads XOR the chunk -> conflict-free b128
// LDS reads with linear DMA (validated R6, conflicts == 0).
// GroupNorm fused into av epilogue (each wn-wave owns ONE 32-ch group/row).
//
// ws layout (shorts):
//   Qb  [8192][1024]            @ 0        (16 MB)
//   Kb  [8192][1024]            @ 8M       (16 MB)
//   Vt  [1024][8192] transposed @ 16M      (16 MB)
//   Ab  [2*4096][4096]          @ 24M      (64 MB)   } aliased:
//   Xb  [8192][1024]            @ 24M      (16 MB)   } Xb/WT dead before
//   WT  [3072][1024]            @ 32M      ( 6 MB)   } score writes Ab
// ---------------------------------------------------------------------------

typedef __attribute__((ext_vector_type(8))) short bf16x8;
typedef __attribute__((ext_vector_type(4))) short bf16x4;
typedef __attribute__((ext_vector_type(4))) float f32x4;

#define MFMA16(a, b, c) __builtin_amdgcn_mfma_f32_16x16x32_bf16(a, b, c, 0, 0, 0)

static __device__ __forceinline__ short f2bf(float f) {
  unsigned u = __builtin_bit_cast(unsigned, f);
  u = (u + 0x7fffu + ((u >> 16) & 1u)) >> 16;
  return (short)u;
}

static __device__ __forceinline__ float fast_silu(float v) {
  // v / (1+e^-v) with v_rcp_f32 (~1 ulp) instead of the 10-instr exact div
  return v * __builtin_amdgcn_rcpf(1.f + __expf(-v));
}

static __device__ __forceinline__ void gl_lds16(const void* g, void* l) {
  __builtin_amdgcn_global_load_lds(
      (const __attribute__((address_space(1))) void*)g,
      (__attribute__((address_space(3))) void*)l, 16, 0, 0);
}

// swizzled column offset for element (row, col) in a swizzled buffer
static __device__ __forceinline__ int swzc(int col, int row) {
  return (((col >> 3) ^ (row & 7)) << 3) | (col & 7);
}

#define T_LEN 4096
#define CIN 1024

// log2(0.99609375)
#define LOG2G (-0.0056465633f)
// log2(10000)/32
#define L2IF (0.41524101f)

// ---------------------------------------------------------------------------
// Kernel A+B merged: blocks [0,4096): X fp32->bf16 swizzled copy;
// blocks [4096,4864): W transpose into WT (swizzled).
// ---------------------------------------------------------------------------
__global__ __launch_bounds__(256)
void prep_kernel(const float* __restrict__ X, short* __restrict__ Xb,
                 const float* __restrict__ Wq, const float* __restrict__ Wk,
                 const float* __restrict__ Wv, short* __restrict__ WT) {
  __shared__ short tile[64][72];
  const int bx = blockIdx.x;
  const int tid = threadIdx.x;
  if (bx < 4096) {
    const int gid = bx * 256 + tid;  // 16B-chunk id
    const int row = gid >> 7;
    const int c = gid & 127;
    const float* s = &X[(size_t)gid * 8];
    float4 f0 = *(const float4*)s;
    float4 f1 = *(const float4*)(s + 4);
    bf16x8 v = {f2bf(f0.x), f2bf(f0.y), f2bf(f0.z), f2bf(f0.w),
                f2bf(f1.x), f2bf(f1.y), f2bf(f1.z), f2bf(f1.w)};
    const int pc = (c & 0x78) | ((c ^ row) & 7);
    *(bf16x8*)&Xb[(size_t)row * 1024 + pc * 8] = v;
    return;
  }
  const int bx2 = bx - 4096;  // 0..767
  const int k0 = (bx2 & 15) * 64, n0 = ((bx2 >> 4) & 15) * 64, mat = bx2 >> 8;
  const float* __restrict__ W = (mat == 0) ? Wq : (mat == 1) ? Wk : Wv;
  const int r = tid >> 4, c = tid & 15;
#pragma unroll
  for (int i = 0; i < 4; ++i) {
    int row = r + 16 * i;
    float4 f = *(const float4*)&W[(size_t)(k0 + row) * CIN + n0 + c * 4];
    tile[c * 4 + 0][row] = f2bf(f.x);
    tile[c * 4 + 1][row] = f2bf(f.y);
    tile[c * 4 + 2][row] = f2bf(f.z);
    tile[c * 4 + 3][row] = f2bf(f.w);
  }
  __syncthreads();
  const int n = tid >> 2, seg = tid & 3;
  bf16x8 lo = *(const bf16x8*)&tile[n][seg * 16];
  bf16x8 hi = *(const bf16x8*)&tile[n][seg * 16 + 8];
  const int R = mat * 1024 + n0 + n;
  const int a0 = (k0 >> 3) + seg * 2;
  short* base = &WT[(size_t)R * CIN];
  *(bf16x8*)&base[(a0 ^ (n & 7)) * 8] = lo;
  *(bf16x8*)&base[((a0 + 1) ^ (n & 7)) * 8] = hi;
}

// ---------------------------------------------------------------------------
// Shared tile-GEMM machinery (R6 single-buffer, 256-thread blocks).
// ---------------------------------------------------------------------------
#define GEMM_DECLS()                                   \
  const int tid = threadIdx.x;                         \
  const int lane = tid & 63, wave = tid >> 6;          \
  const int wm = wave >> 1, wn = wave & 1;             \
  const int l15 = lane & 15, quad = lane >> 4;         \
  const int srow = tid >> 3;                           \
  const int scol = (tid & 7) * 8;                      \
  const int asw = (l15 & 7);

#define ACC_INIT4(acc)                                 \
  _Pragma("unroll") for (int i = 0; i < 4; ++i)        \
  _Pragma("unroll") for (int j = 0; j < 4; ++j) {      \
    f32x4 z = {0.f, 0.f, 0.f, 0.f};                    \
    acc[i][j] = z;                                     \
  }

#define STAGE_TILE(dst, src, ld, r0, k0, nrows)        \
  _Pragma("unroll") for (int i = 0; i < (nrows) / 32; ++i) \
    gl_lds16(&src[(size_t)((r0) + i * 32 + srow) * (ld) + (k0) + scol], \
             &dst[i * 32 + srow][scol]);

#define FRAG_MFMA44(As, Bs, acc)                                            \
  {                                                                         \
    bf16x8 af[4][2], bfr[4][2];                                             \
    _Pragma("unroll") for (int im = 0; im < 4; ++im)                        \
    _Pragma("unroll") for (int ks = 0; ks < 2; ++ks)                        \
      af[im][ks] = *(const bf16x8*)&As[wm * 64 + im * 16 + l15]             \
                       [((ks * 4 + quad) ^ asw) * 8];                       \
    _Pragma("unroll") for (int in = 0; in < 4; ++in)                        \
    _Pragma("unroll") for (int ks = 0; ks < 2; ++ks)                        \
      bfr[in][ks] = *(const bf16x8*)&Bs[wn * 64 + in * 16 + l15]            \
                        [((ks * 4 + quad) ^ asw) * 8];                      \
    _Pragma("unroll") for (int ks = 0; ks < 2; ++ks)                        \
    _Pragma("unroll") for (int im = 0; im < 4; ++im)                        \
    _Pragma("unroll") for (int in = 0; in < 4; ++in)                        \
      acc[im][in] = MFMA16(af[im][ks], bfr[in][ks], acc[im][in]);           \
  }

// ---------------------------------------------------------------------------
// Kernel C: QKV GEMM. C[m][c] = sum_k Xb[m][k] WT[c][k].  M=8192, N=3072.
// grid (64 m-tiles, 24 c-tiles). Epilogue: rope(Q,K cols<64, block-uniform
// guard) + fast silu.  (R6 proven structure.)
// ---------------------------------------------------------------------------
__global__ __launch_bounds__(256, 2)
void qkv_gemm(const short* __restrict__ Xb, const short* __restrict__ WT,
              short* __restrict__ Qb, short* __restrict__ Kb,
              short* __restrict__ Vt) {
  __shared__ __align__(16) short As[128][64];
  __shared__ __align__(16) short Bs[128][64];
  GEMM_DECLS();
  const int m0 = blockIdx.x * 128;
  const int c0 = blockIdx.y * 128;

  f32x4 acc[4][4];
  ACC_INIT4(acc);

  for (int k0 = 0; k0 < CIN; k0 += 64) {
    __syncthreads();
    STAGE_TILE(As, Xb, CIN, m0, k0, 128);
    STAGE_TILE(Bs, WT, CIN, c0, k0, 128);
    __syncthreads();
    FRAG_MFMA44(As, Bs, acc);
  }

  const int mat = (c0 >> 10);  // block-uniform: 0=Q 1=K 2=V
  const bool ropeBlk = (mat < 2) && ((c0 & 1023) == 0);
#pragma unroll
  for (int im = 0; im < 4; ++im) {
#pragma unroll
    for (int in = 0; in < 4; ++in) {
      const int c = c0 + wn * 64 + in * 16 + l15;
      const int colm = c & 1023;
      const int mbase = m0 + wm * 64 + im * 16 + quad * 4;
      short vv[4];
      if (ropeBlk && colm < 64) {  // wave-uniform (colm<64 indep of lane)
        const float invf = exp2f(-L2IF * (float)(colm >> 1));
#pragma unroll
        for (int r = 0; r < 4; ++r) {
          float v = acc[im][in][r];
          int t = (mbase + r) & (T_LEN - 1);
          float partner = __shfl_xor(v, 1, 64);
          float ang = (float)t * invf;
          float s_ = __sinf(ang), c_ = __cosf(ang);
          v = (colm & 1) ? (v * c_ + partner * s_) : (v * c_ - partner * s_);
          vv[r] = f2bf(fast_silu(v));
        }
      } else {
#pragma unroll
        for (int r = 0; r < 4; ++r) vv[r] = f2bf(fast_silu(acc[im][in][r]));
      }
      if (mat == 0) {
#pragma unroll
        for (int r = 0; r < 4; ++r)
          Qb[(size_t)(mbase + r) * 1024 + swzc(colm, mbase + r)] = vv[r];
      } else if (mat == 1) {
#pragma unroll
        for (int r = 0; r < 4; ++r)
          Kb[(size_t)(mbase + r) * 1024 + swzc(colm, mbase + r)] = vv[r];
      } else {
        bf16x4 v4 = {vv[0], vv[1], vv[2], vv[3]};
        *(bf16x4*)&Vt[(size_t)colm * 8192 +
                      (((mbase >> 3) ^ (colm & 7)) << 3) + (mbase & 7)] = v4;
      }
    }
  }
}

// ---------------------------------------------------------------------------
// Kernel D: A' = decay o (Q K^T), bf16 swizzled. Triangular grid: 528 tiles
// (si>=ti) per batch, grid (528, 2). Uniform work per block.
// R11: BK=128 (8 iters instead of 16): halves exposed-latency stage windows.
// LDS 64KB x 2 blk/CU = 128 <= 160 KB. Chunk-XOR swizzle unchanged (XOR is
// within aligned-8 chunk groups; chunk bit 3 passes through).
// ---------------------------------------------------------------------------
__global__ __launch_bounds__(256, 2)
void score_kernel(const short* __restrict__ Qb, const short* __restrict__ Kb,
                  short* __restrict__ Ab) {
  int idx = blockIdx.x;
  int ti = 0;
  while (idx >= 32 - ti) { idx -= 32 - ti; ++ti; }
  const int si = ti + idx;
  const int b = blockIdx.y;
  const int s0 = si * 128, t0 = ti * 128;

  __shared__ __align__(16) short Qs[128][128];
  __shared__ __align__(16) short Ks[128][128];

  const int tid = threadIdx.x;
  const int lane = tid & 63, wave = tid >> 6;
  const int wm = wave >> 1, wn = wave & 1;
  const int l15 = lane & 15, quad = lane >> 4;
  const int srow2 = tid >> 4;        // 0..15
  const int scol2 = (tid & 15) * 8;  // 0..120
  const int asw = l15 & 7;

  f32x4 acc[4][4];
  ACC_INIT4(acc);

#pragma unroll 1
  for (int k0 = 0; k0 < 1024; k0 += 128) {
    __syncthreads();
#pragma unroll
    for (int i = 0; i < 8; ++i) {
      gl_lds16(&Qb[(size_t)(b * T_LEN + t0 + i * 16 + srow2) * 1024 + k0 + scol2],
               &Qs[i * 16 + srow2][scol2]);
      gl_lds16(&Kb[(size_t)(b * T_LEN + s0 + i * 16 + srow2) * 1024 + k0 + scol2],
               &Ks[i * 16 + srow2][scol2]);
    }
    __syncthreads();
#pragma unroll
    for (int ks = 0; ks < 4; ++ks) {
      bf16x8 af[4], bfr[4];
#pragma unroll
      for (int im = 0; im < 4; ++im)
        af[im] = *(const bf16x8*)&Qs[wm * 64 + im * 16 + l15]
                     [((ks * 4 + quad) ^ asw) * 8];
#pragma unroll
      for (int in = 0; in < 4; ++in)
        bfr[in] = *(const bf16x8*)&Ks[wn * 64 + in * 16 + l15]
                      [((ks * 4 + quad) ^ asw) * 8];
#pragma unroll
      for (int im = 0; im < 4; ++im)
#pragma unroll
        for (int in = 0; in < 4; ++in)
          acc[im][in] = MFMA16(af[im], bfr[in], acc[im][in]);
    }
  }

#pragma unroll
  for (int im = 0; im < 4; ++im) {
#pragma unroll
    for (int in = 0; in < 4; ++in) {
      int s = s0 + wn * 64 + in * 16 + l15;
#pragma unroll
      for (int r = 0; r < 4; ++r) {
        int t = t0 + wm * 64 + im * 16 + quad * 4 + r;
        int d = s - t;
        float v = acc[im][in][r];
        v = (d < 0) ? 0.f : v * exp2f((float)d * LOG2G);
        Ab[((size_t)(b * T_LEN + t)) * T_LEN + swzc(s, t)] = f2bf(v);
      }
    }
  }
}

// ---------------------------------------------------------------------------
// Kernel E: out = GroupNorm(A' V) (fp32).
// R11: R10 structure (BM=128, 512-thr 8-wave, BN=128, BK=64, grid (16,2,8)
// = 256 blocks = 1 blk/CU) + 3-buffer depth-2 counted-vmcnt pipeline:
// prologue stages iters 0,1; per iter {s_barrier; stage it+2; vmcnt(8);
// s_barrier; compute}. Loads stay in flight across barriers (T4); at
// 1 blk/CU there is no inter-block overlap to mask latency, so this is
// T4's regime (R9's null was at 2 blk/CU). NO sched_barrier (m141).
// LDS 96 KB (3 x 32 KB), 1 blk/CU.
// GN fused: each wn-wave owns ONE complete 32-ch group per row
// (in-pair {n, n+16} x 16 l15 lanes) -> shfl_xor(1,2,4,8), no LDS pass.
// ---------------------------------------------------------------------------
__global__ __launch_bounds__(512, 1)
void av_kernel(const short* __restrict__ Ab, const short* __restrict__ Vt,
               const float* __restrict__ gw, const float* __restrict__ gb,
               float* __restrict__ Out) {
  const int p = blockIdx.x, b = blockIdx.y, di = blockIdx.z;
  const int n0 = di * 128;

  __shared__ __align__(16) short As2[3][128][64];
  __shared__ __align__(16) short Vs[3][128][64];

  const int tid = threadIdx.x;
  const int lane = tid & 63, wave = tid >> 6;  // 8 waves
  const int wm = wave >> 2, wn = wave & 3;     // 2 x 4
  const int l15 = lane & 15, quad = lane >> 4;
  const int srow = tid >> 3;                   // 0..63 (512 thr)
  const int scol = (tid & 7) * 8;
  const int asw = l15 & 7;

  // gamma/beta for this thread's 2 channel positions (in = 0..1)
  float w2[2], b2[2];
#pragma unroll
  for (int in = 0; in < 2; ++in) {
    int n = n0 + wn * 32 + in * 16 + l15;
    w2[in] = gw[n];
    b2[in] = gb[n];
  }

  // stage helpers: 4 gl_lds16 per thread per iteration (2 A + 2 V)
#define AV_STAGE(buf, s)                                                      \
  {                                                                           \
    gl_lds16(&Ab[(size_t)(b * T_LEN + t0 + srow) * T_LEN + (s) + scol],       \
             &As2[buf][srow][scol]);                                          \
    gl_lds16(&Ab[(size_t)(b * T_LEN + t0 + 64 + srow) * T_LEN + (s) + scol],  \
             &As2[buf][64 + srow][scol]);                                     \
    gl_lds16(&Vt[(size_t)(n0 + srow) * 8192 + b * T_LEN + (s) + scol],        \
             &Vs[buf][srow][scol]);                                           \
    gl_lds16(&Vt[(size_t)(n0 + 64 + srow) * 8192 + b * T_LEN + (s) + scol],   \
             &Vs[buf][64 + srow][scol]);                                      \
  }

#pragma unroll 1
  for (int half = 0; half < 2; ++half) {
    const int ti2 = half ? (31 - p) : p;  // 128-row tile index
    const int t0 = ti2 * 128;
    const int nIt = (T_LEN - t0) >> 6;    // >= 2 always (ti2 <= 31)

    f32x4 acc[4][2];
#pragma unroll
    for (int i = 0; i < 4; ++i)
#pragma unroll
      for (int j = 0; j < 2; ++j) {
        f32x4 z = {0.f, 0.f, 0.f, 0.f};
        acc[i][j] = z;
      }

    // full drain (incl. prev half's epilogue stores -> clean vmcnt counts)
    __syncthreads();
    AV_STAGE(0, t0);
    AV_STAGE(1, t0 + 64);

    int cur = 0;
#pragma unroll 1
    for (int it = 0; it < nIt; ++it) {
      // (a): all waves done reading buf[nx2] (it was 'cur' at iter it-1)
      __builtin_amdgcn_s_barrier();
      const int nx2 = (cur >= 1) ? cur - 1 : 2;  // (cur+2)%3
      if (it + 2 < nIt) {
        const int s = t0 + ((it + 2) << 6);
        AV_STAGE(nx2, s);
        // in-flight/thread: 4(it)+4(it+1)+4(it+2)=12 -> wait oldest 4
        asm volatile("s_waitcnt vmcnt(8)" ::: "memory");
      } else if (it + 1 < nIt) {
        asm volatile("s_waitcnt vmcnt(4)" ::: "memory");
      } else {
        asm volatile("s_waitcnt vmcnt(0)" ::: "memory");
      }
      // (b): all waves' iter-it DMA landed in LDS
      __builtin_amdgcn_s_barrier();

      bf16x8 af[4][2], bfr[2][2];
#pragma unroll
      for (int im = 0; im < 4; ++im)
#pragma unroll
        for (int ks = 0; ks < 2; ++ks)
          af[im][ks] = *(const bf16x8*)&As2[cur][wm * 64 + im * 16 + l15]
                           [((ks * 4 + quad) ^ asw) * 8];
#pragma unroll
      for (int in = 0; in < 2; ++in)
#pragma unroll
        for (int ks = 0; ks < 2; ++ks)
          bfr[in][ks] = *(const bf16x8*)&Vs[cur][wn * 32 + in * 16 + l15]
                            [((ks * 4 + quad) ^ asw) * 8];
#pragma unroll
      for (int ks = 0; ks < 2; ++ks)
#pragma unroll
        for (int im = 0; im < 4; ++im)
#pragma unroll
          for (int in = 0; in < 2; ++in)
            acc[im][in] = MFMA16(af[im][ks], bfr[in][ks], acc[im][in]);

      cur = (cur == 2) ? 0 : cur + 1;
    }

    // fused GroupNorm + store. Wave's group = cols [n0+wn*32, +32).
#pragma unroll
    for (int im = 0; im < 4; ++im) {
#pragma unroll
      for (int r = 0; r < 4; ++r) {
        int t = t0 + wm * 64 + im * 16 + quad * 4 + r;
        float* orow = &Out[((size_t)(b * T_LEN + t)) * 1024];
        float a0 = acc[im][0][r], a1 = acc[im][1][r];
        float s = a0 + a1;
        float q = a0 * a0 + a1 * a1;
        s += __shfl_xor(s, 1, 64);
        q += __shfl_xor(q, 1, 64);
        s += __shfl_xor(s, 2, 64);
        q += __shfl_xor(q, 2, 64);
        s += __shfl_xor(s, 4, 64);
        q += __shfl_xor(q, 4, 64);
        s += __shfl_xor(s, 8, 64);
        q += __shfl_xor(q, 8, 64);
        float mean = s * (1.f / 32.f);
        float var = q * (1.f / 32.f) - mean * mean;
        float rstd = rsqrtf(var + 1e-6f);
        int n = n0 + wn * 32 + l15;
        orow[n] = (a0 - mean) * rstd * w2[0] + b2[0];
        orow[n + 16] = (a1 - mean) * rstd * w2[1] + b2[1];
      }
    }
  }
#undef AV_STAGE
}

// ---------------------------------------------------------------------------
extern "C" void kernel_launch(void* const* d_in, const int* in_sizes, int n_in,
                              void* d_out, int out_size, void* d_ws,
                              size_t ws_size, hipStream_t stream) {
  const float* X = (const float*)d_in[0];
  const float* Wq = (const float*)d_in[1];
  const float* Wk = (const float*)d_in[2];
  const float* Wv = (const float*)d_in[3];
  const float* gw = (const float*)d_in[4];
  const float* gb = (const float*)d_in[5];
  float* Out = (float*)d_out;

  short* Qb = (short*)d_ws;                        // 16 MB
  short* Kb = Qb + (size_t)8192 * 1024;            // 16 MB
  short* Vt = Kb + (size_t)8192 * 1024;            // 16 MB (transposed)
  short* Ab = Vt + (size_t)8192 * 1024;            // 64 MB
  short* Xb = Ab;                                  // aliases Ab (dead after qkv)
  short* WT = Xb + (size_t)8192 * 1024;            // 6 MB

  prep_kernel<<<4864, 256, 0, stream>>>(X, Xb, Wq, Wk, Wv, WT);
  qkv_gemm<<<dim3(64, 24), 256, 0, stream>>>(Xb, WT, Qb, Kb, Vt);
  score_kernel<<<dim3(528, 2), 256, 0, stream>>>(Qb, Kb, Ab);
  av_kernel<<<dim3(16, 2, 8), 512, 0, stream>>>(Ab, Vt, gw, gb, Out);
}

// Round 5
// 280.858 us; speedup vs baseline: 1.0087x; 1.0087x over previous
//
#include <hip/hip_runtime.h>

// ---------------------------------------------------------------------------
// SingleHeadQKV: X@{Wq,Wk,Wv} -> rope+silu -> decay-masked QK^T -> @V -> GN
// B=2, T=4096, C=1024.
// R12: av rebuilt to the EXACT m97/qkv structure (4 waves, wave=64x64,
// acc[4][4], 128^2 tile, BK=64, single-buffer 2-barrier, 32KB LDS,
// 2 blk/CU). R10/R11's 8-wave 64x32-per-wave shape did 768 B LDS-read per
// MFMA vs 512 here; ds_read_b128 throughput was the bound (scheduling
// nulls R9/R11 proved it's not latency). Grid = flat 512 with statistical
// pairing: block k (b=0,tile q) + block k+256 (b=1,tile 31-q) share a CU
// -> uniform 66 iters/CU. di = fastest grid bits -> the 8 A-sharing
// blocks dispatch adjacently (cross-XCD LLC dedup of A stream).
// score reverted to R6 BK=64 (R11's BK=128 was neutral-negative).
// qkv/prep unchanged (proven).
// Staging = linear global_load_lds(16B) from PRE-SWIZZLED buffers (phys 16B
// chunk = (col>>3)^(row&7)); frag reads XOR the chunk -> conflict-free b128
// LDS reads with linear DMA (validated R6, conflicts == 0).
// GroupNorm fused into av epilogue (each wn-wave owns 2 complete 32-ch
// groups per row; shfl_xor(1,2,4,8) over l15 lanes).
//
// ws layout (shorts):
//   Qb  [8192][1024]            @ 0        (16 MB)
//   Kb  [8192][1024]            @ 8M       (16 MB)
//   Vt  [1024][8192] transposed @ 16M      (16 MB)
//   Ab  [2*4096][4096]          @ 24M      (64 MB)   } aliased:
//   Xb  [8192][1024]            @ 24M      (16 MB)   } Xb/WT dead before
//   WT  [3072][1024]            @ 32M      ( 6 MB)   } score writes Ab
// ---------------------------------------------------------------------------

typedef __attribute__((ext_vector_type(8))) short bf16x8;
typedef __attribute__((ext_vector_type(4))) short bf16x4;
typedef __attribute__((ext_vector_type(4))) float f32x4;

#define MFMA16(a, b, c) __builtin_amdgcn_mfma_f32_16x16x32_bf16(a, b, c, 0, 0, 0)

static __device__ __forceinline__ short f2bf(float f) {
  unsigned u = __builtin_bit_cast(unsigned, f);
  u = (u + 0x7fffu + ((u >> 16) & 1u)) >> 16;
  return (short)u;
}

static __device__ __forceinline__ float fast_silu(float v) {
  // v / (1+e^-v) with v_rcp_f32 (~1 ulp) instead of the 10-instr exact div
  return v * __builtin_amdgcn_rcpf(1.f + __expf(-v));
}

static __device__ __forceinline__ void gl_lds16(const void* g, void* l) {
  __builtin_amdgcn_global_load_lds(
      (const __attribute__((address_space(1))) void*)g,
      (__attribute__((address_space(3))) void*)l, 16, 0, 0);
}

// swizzled column offset for element (row, col) in a swizzled buffer
static __device__ __forceinline__ int swzc(int col, int row) {
  return (((col >> 3) ^ (row & 7)) << 3) | (col & 7);
}

#define T_LEN 4096
#define CIN 1024

// log2(0.99609375)
#define LOG2G (-0.0056465633f)
// log2(10000)/32
#define L2IF (0.41524101f)

// ---------------------------------------------------------------------------
// Kernel A+B merged: blocks [0,4096): X fp32->bf16 swizzled copy;
// blocks [4096,4864): W transpose into WT (swizzled).
// ---------------------------------------------------------------------------
__global__ __launch_bounds__(256)
void prep_kernel(const float* __restrict__ X, short* __restrict__ Xb,
                 const float* __restrict__ Wq, const float* __restrict__ Wk,
                 const float* __restrict__ Wv, short* __restrict__ WT) {
  __shared__ short tile[64][72];
  const int bx = blockIdx.x;
  const int tid = threadIdx.x;
  if (bx < 4096) {
    const int gid = bx * 256 + tid;  // 16B-chunk id
    const int row = gid >> 7;
    const int c = gid & 127;
    const float* s = &X[(size_t)gid * 8];
    float4 f0 = *(const float4*)s;
    float4 f1 = *(const float4*)(s + 4);
    bf16x8 v = {f2bf(f0.x), f2bf(f0.y), f2bf(f0.z), f2bf(f0.w),
                f2bf(f1.x), f2bf(f1.y), f2bf(f1.z), f2bf(f1.w)};
    const int pc = (c & 0x78) | ((c ^ row) & 7);
    *(bf16x8*)&Xb[(size_t)row * 1024 + pc * 8] = v;
    return;
  }
  const int bx2 = bx - 4096;  // 0..767
  const int k0 = (bx2 & 15) * 64, n0 = ((bx2 >> 4) & 15) * 64, mat = bx2 >> 8;
  const float* __restrict__ W = (mat == 0) ? Wq : (mat == 1) ? Wk : Wv;
  const int r = tid >> 4, c = tid & 15;
#pragma unroll
  for (int i = 0; i < 4; ++i) {
    int row = r + 16 * i;
    float4 f = *(const float4*)&W[(size_t)(k0 + row) * CIN + n0 + c * 4];
    tile[c * 4 + 0][row] = f2bf(f.x);
    tile[c * 4 + 1][row] = f2bf(f.y);
    tile[c * 4 + 2][row] = f2bf(f.z);
    tile[c * 4 + 3][row] = f2bf(f.w);
  }
  __syncthreads();
  const int n = tid >> 2, seg = tid & 3;
  bf16x8 lo = *(const bf16x8*)&tile[n][seg * 16];
  bf16x8 hi = *(const bf16x8*)&tile[n][seg * 16 + 8];
  const int R = mat * 1024 + n0 + n;
  const int a0 = (k0 >> 3) + seg * 2;
  short* base = &WT[(size_t)R * CIN];
  *(bf16x8*)&base[(a0 ^ (n & 7)) * 8] = lo;
  *(bf16x8*)&base[((a0 + 1) ^ (n & 7)) * 8] = hi;
}

// ---------------------------------------------------------------------------
// Shared tile-GEMM machinery (R6 single-buffer, 256-thread blocks).
// ---------------------------------------------------------------------------
#define GEMM_DECLS()                                   \
  const int tid = threadIdx.x;                         \
  const int lane = tid & 63, wave = tid >> 6;          \
  const int wm = wave >> 1, wn = wave & 1;             \
  const int l15 = lane & 15, quad = lane >> 4;         \
  const int srow = tid >> 3;                           \
  const int scol = (tid & 7) * 8;                      \
  const int asw = (l15 & 7);

#define ACC_INIT4(acc)                                 \
  _Pragma("unroll") for (int i = 0; i < 4; ++i)        \
  _Pragma("unroll") for (int j = 0; j < 4; ++j) {      \
    f32x4 z = {0.f, 0.f, 0.f, 0.f};                    \
    acc[i][j] = z;                                     \
  }

#define STAGE_TILE(dst, src, ld, r0, k0, nrows)        \
  _Pragma("unroll") for (int i = 0; i < (nrows) / 32; ++i) \
    gl_lds16(&src[(size_t)((r0) + i * 32 + srow) * (ld) + (k0) + scol], \
             &dst[i * 32 + srow][scol]);

#define FRAG_MFMA44(As, Bs, acc)                                            \
  {                                                                         \
    bf16x8 af[4][2], bfr[4][2];                                             \
    _Pragma("unroll") for (int im = 0; im < 4; ++im)                        \
    _Pragma("unroll") for (int ks = 0; ks < 2; ++ks)                        \
      af[im][ks] = *(const bf16x8*)&As[wm * 64 + im * 16 + l15]             \
                       [((ks * 4 + quad) ^ asw) * 8];                       \
    _Pragma("unroll") for (int in = 0; in < 4; ++in)                        \
    _Pragma("unroll") for (int ks = 0; ks < 2; ++ks)                        \
      bfr[in][ks] = *(const bf16x8*)&Bs[wn * 64 + in * 16 + l15]            \
                        [((ks * 4 + quad) ^ asw) * 8];                      \
    _Pragma("unroll") for (int ks = 0; ks < 2; ++ks)                        \
    _Pragma("unroll") for (int im = 0; im < 4; ++im)                        \
    _Pragma("unroll") for (int in = 0; in < 4; ++in)                        \
      acc[im][in] = MFMA16(af[im][ks], bfr[in][ks], acc[im][in]);           \
  }

// ---------------------------------------------------------------------------
// Kernel C: QKV GEMM. C[m][c] = sum_k Xb[m][k] WT[c][k].  M=8192, N=3072.
// grid (64 m-tiles, 24 c-tiles). Epilogue: rope(Q,K cols<64, block-uniform
// guard) + fast silu.  (R6 proven structure.)
// ---------------------------------------------------------------------------
__global__ __launch_bounds__(256, 2)
void qkv_gemm(const short* __restrict__ Xb, const short* __restrict__ WT,
              short* __restrict__ Qb, short* __restrict__ Kb,
              short* __restrict__ Vt) {
  __shared__ __align__(16) short As[128][64];
  __shared__ __align__(16) short Bs[128][64];
  GEMM_DECLS();
  const int m0 = blockIdx.x * 128;
  const int c0 = blockIdx.y * 128;

  f32x4 acc[4][4];
  ACC_INIT4(acc);

  for (int k0 = 0; k0 < CIN; k0 += 64) {
    __syncthreads();
    STAGE_TILE(As, Xb, CIN, m0, k0, 128);
    STAGE_TILE(Bs, WT, CIN, c0, k0, 128);
    __syncthreads();
    FRAG_MFMA44(As, Bs, acc);
  }

  const int mat = (c0 >> 10);  // block-uniform: 0=Q 1=K 2=V
  const bool ropeBlk = (mat < 2) && ((c0 & 1023) == 0);
#pragma unroll
  for (int im = 0; im < 4; ++im) {
#pragma unroll
    for (int in = 0; in < 4; ++in) {
      const int c = c0 + wn * 64 + in * 16 + l15;
      const int colm = c & 1023;
      const int mbase = m0 + wm * 64 + im * 16 + quad * 4;
      short vv[4];
      if (ropeBlk && colm < 64) {  // wave-uniform (colm<64 indep of lane)
        const float invf = exp2f(-L2IF * (float)(colm >> 1));
#pragma unroll
        for (int r = 0; r < 4; ++r) {
          float v = acc[im][in][r];
          int t = (mbase + r) & (T_LEN - 1);
          float partner = __shfl_xor(v, 1, 64);
          float ang = (float)t * invf;
          float s_ = __sinf(ang), c_ = __cosf(ang);
          v = (colm & 1) ? (v * c_ + partner * s_) : (v * c_ - partner * s_);
          vv[r] = f2bf(fast_silu(v));
        }
      } else {
#pragma unroll
        for (int r = 0; r < 4; ++r) vv[r] = f2bf(fast_silu(acc[im][in][r]));
      }
      if (mat == 0) {
#pragma unroll
        for (int r = 0; r < 4; ++r)
          Qb[(size_t)(mbase + r) * 1024 + swzc(colm, mbase + r)] = vv[r];
      } else if (mat == 1) {
#pragma unroll
        for (int r = 0; r < 4; ++r)
          Kb[(size_t)(mbase + r) * 1024 + swzc(colm, mbase + r)] = vv[r];
      } else {
        bf16x4 v4 = {vv[0], vv[1], vv[2], vv[3]};
        *(bf16x4*)&Vt[(size_t)colm * 8192 +
                      (((mbase >> 3) ^ (colm & 7)) << 3) + (mbase & 7)] = v4;
      }
    }
  }
}

// ---------------------------------------------------------------------------
// Kernel D: A' = decay o (Q K^T), bf16 swizzled. Triangular grid: 528 tiles
// (si>=ti) per batch, grid (528, 2). Uniform work per block.
// (R6 proven structure, reverted from R11's BK=128.)
// ---------------------------------------------------------------------------
__global__ __launch_bounds__(256, 2)
void score_kernel(const short* __restrict__ Qb, const short* __restrict__ Kb,
                  short* __restrict__ Ab) {
  int idx = blockIdx.x;
  int ti = 0;
  while (idx >= 32 - ti) { idx -= 32 - ti; ++ti; }
  const int si = ti + idx;
  const int b = blockIdx.y;
  const int s0 = si * 128, t0 = ti * 128;

  __shared__ __align__(16) short Qs[128][64];
  __shared__ __align__(16) short Ks[128][64];
  GEMM_DECLS();

  f32x4 acc[4][4];
  ACC_INIT4(acc);

  for (int k0 = 0; k0 < 1024; k0 += 64) {
    __syncthreads();
    STAGE_TILE(Qs, Qb, 1024, b * T_LEN + t0, k0, 128);
    STAGE_TILE(Ks, Kb, 1024, b * T_LEN + s0, k0, 128);
    __syncthreads();
    FRAG_MFMA44(Qs, Ks, acc);
  }

#pragma unroll
  for (int im = 0; im < 4; ++im) {
#pragma unroll
    for (int in = 0; in < 4; ++in) {
      int s = s0 + wn * 64 + in * 16 + l15;
#pragma unroll
      for (int r = 0; r < 4; ++r) {
        int t = t0 + wm * 64 + im * 16 + quad * 4 + r;
        int d = s - t;
        float v = acc[im][in][r];
        v = (d < 0) ? 0.f : v * exp2f((float)d * LOG2G);
        Ab[((size_t)(b * T_LEN + t)) * T_LEN + swzc(s, t)] = f2bf(v);
      }
    }
  }
}

// ---------------------------------------------------------------------------
// Kernel E: out = GroupNorm(A' V) (fp32).
// R12: m97/qkv structure — 4 waves (2x2), wave=64x64 (acc[4][4]), tile
// 128x128, BK=64, single-buffer 2-barrier, 32KB LDS, 2 blk/CU.
// Flat grid 512: wgid = di(3b) | q(5b) | half(1b). b = half;
// ti2 = half ? 31-q : q. Blocks k and k+256 share CU c=k (round-robin
// dispatch) -> per-CU iters (64-2q)+(2+2q) = 66, uniform. di fastest ->
// 8 A-sharing blocks dispatch adjacently -> LLC dedups the A stream.
// Long tiles (q=0) dispatch first.
// GN fused: each wn-wave owns 2 complete 32-ch groups per row
// (in-pair {2g,2g+1} x l15) -> shfl_xor(1,2,4,8), no LDS pass.
// ---------------------------------------------------------------------------
__global__ __launch_bounds__(256, 2)
void av_kernel(const short* __restrict__ Ab, const short* __restrict__ Vt,
               const float* __restrict__ gw, const float* __restrict__ gb,
               float* __restrict__ Out) {
  const int wgid = blockIdx.x;
  const int di = wgid & 7;
  const int q = (wgid >> 3) & 31;
  const int half = wgid >> 8;
  const int b = half;
  const int ti2 = half ? (31 - q) : q;
  const int t0 = ti2 * 128;
  const int n0 = di * 128;
  const int nIt = (T_LEN - t0) >> 6;  // 64 - 2*ti2

  __shared__ __align__(16) short As2[128][64];
  __shared__ __align__(16) short Vs[128][64];
  GEMM_DECLS();

  // gamma/beta for this thread's 4 channel positions (in = 0..3)
  float w4[4], b4[4];
#pragma unroll
  for (int in = 0; in < 4; ++in) {
    int n = n0 + wn * 64 + in * 16 + l15;
    w4[in] = gw[n];
    b4[in] = gb[n];
  }

  f32x4 acc[4][4];
  ACC_INIT4(acc);

#pragma unroll 1
  for (int it = 0; it < nIt; ++it) {
    const int s = t0 + (it << 6);
    __syncthreads();
    STAGE_TILE(As2, Ab, T_LEN, b * T_LEN + t0, s, 128);
    STAGE_TILE(Vs, Vt, 8192, n0, b * T_LEN + s, 128);
    __syncthreads();
    FRAG_MFMA44(As2, Vs, acc);
  }

  // fused GroupNorm + store. Wave's cols [n0+wn*64, +64) = groups {2g,2g+1}.
#pragma unroll
  for (int im = 0; im < 4; ++im) {
#pragma unroll
    for (int r = 0; r < 4; ++r) {
      int t = t0 + wm * 64 + im * 16 + quad * 4 + r;
      float* orow = &Out[((size_t)(b * T_LEN + t)) * 1024];
#pragma unroll
      for (int g = 0; g < 2; ++g) {
        float a0 = acc[im][g * 2][r], a1 = acc[im][g * 2 + 1][r];
        float s = a0 + a1;
        float qq = a0 * a0 + a1 * a1;
        s += __shfl_xor(s, 1, 64);
        qq += __shfl_xor(qq, 1, 64);
        s += __shfl_xor(s, 2, 64);
        qq += __shfl_xor(qq, 2, 64);
        s += __shfl_xor(s, 4, 64);
        qq += __shfl_xor(qq, 4, 64);
        s += __shfl_xor(s, 8, 64);
        qq += __shfl_xor(qq, 8, 64);
        float mean = s * (1.f / 32.f);
        float var = qq * (1.f / 32.f) - mean * mean;
        float rstd = rsqrtf(var + 1e-6f);
        int n = n0 + wn * 64 + g * 32 + l15;
        orow[n] = (a0 - mean) * rstd * w4[g * 2] + b4[g * 2];
        orow[n + 16] = (a1 - mean) * rstd * w4[g * 2 + 1] + b4[g * 2 + 1];
      }
    }
  }
}

// ---------------------------------------------------------------------------
extern "C" void kernel_launch(void* const* d_in, const int* in_sizes, int n_in,
                              void* d_out, int out_size, void* d_ws,
                              size_t ws_size, hipStream_t stream) {
  const float* X = (const float*)d_in[0];
  const float* Wq = (const float*)d_in[1];
  const float* Wk = (const float*)d_in[2];
  const float* Wv = (const float*)d_in[3];
  const float* gw = (const float*)d_in[4];
  const float* gb = (const float*)d_in[5];
  float* Out = (float*)d_out;

  short* Qb = (short*)d_ws;                        // 16 MB
  short* Kb = Qb + (size_t)8192 * 1024;            // 16 MB
  short* Vt = Kb + (size_t)8192 * 1024;            // 16 MB (transposed)
  short* Ab = Vt + (size_t)8192 * 1024;            // 64 MB
  short* Xb = Ab;                                  // aliases Ab (dead after qkv)
  short* WT = Xb + (size_t)8192 * 1024;            // 6 MB

  prep_kernel<<<4864, 256, 0, stream>>>(X, Xb, Wq, Wk, Wv, WT);
  qkv_gemm<<<dim3(64, 24), 256, 0, stream>>>(Xb, WT, Qb, Kb, Vt);
  score_kernel<<<dim3(528, 2), 256, 0, stream>>>(Qb, Kb, Ab);
  av_kernel<<<512, 256, 0, stream>>>(Ab, Vt, gw, gb, Out);
}